// Round 7
// baseline (76.148 us; speedup 1.0000x reference)
//
#include <hip/hip_runtime.h>
#include <math.h>

// ---------------------------------------------------------------------------
// MultiRoundDistribution MCMC — bit-exact JAX PRNG (partitionable threefry).
// Round 7: mcmc kernel stripped to a pure LDS-table machine.
//   - draw dispatch precomputes: per-(step,chain) draws, pair-factor rows,
//     exp singles, site/collision metadata, selection weights  -> d_ws
//   - mcmc: block-copy tables to LDS; 48-step loop (x2 unrolled) with only
//     LDS reads, f64 mul/fma chain, branch-free accept; adjacent-site
//     collisions resolved via preloaded alternate row + select (uniform flag)
// N=16384 chains, 1 thread/chain, 256 blocks x 64 threads.
// ---------------------------------------------------------------------------

constexpr int kN = 16384;
constexpr int kL = 48;
constexpr int kM = 4;
constexpr int kR = 7;
constexpr int kSteps = 48;  // n_sweeps(=1) * L

// ---- d_ws layout ----
constexpr int ROWS_OFF = 0;                       // 768 rows x 80B  (site*16+idx)
constexpr int SING_OFF = 61440;                   // 48*4 x 64B  (exp singles)
constexpr int META_OFF = 73728;                   // 50 x {u32 off, u32 site|flag<<8}
constexpr int BB_OFF   = 74128;                   // 21 doubles (b1,b2,b3 per round)
constexpr int TAB_BYTES = 74752;                  // padded to 1KB multiple
constexpr int DRAWS_OFF = 74752;                  // 48*16384 u32

// ---------------- Threefry-2x32 (JAX rotation schedule) ----------------
#define TF_ROUND(rot) do { x0 += x1; x1 = (x1 << (rot)) | (x1 >> (32 - (rot))); x1 ^= x0; } while (0)

__device__ __forceinline__ void tf2(unsigned ka, unsigned kb,
                                    unsigned x0, unsigned x1,
                                    unsigned& o0, unsigned& o1) {
  const unsigned ks2 = ka ^ kb ^ 0x1BD11BDAu;
  x0 += ka; x1 += kb;
  TF_ROUND(13); TF_ROUND(15); TF_ROUND(26); TF_ROUND(6);
  x0 += kb; x1 += ks2 + 1u;
  TF_ROUND(17); TF_ROUND(29); TF_ROUND(16); TF_ROUND(24);
  x0 += ks2; x1 += ka + 2u;
  TF_ROUND(13); TF_ROUND(15); TF_ROUND(26); TF_ROUND(6);
  x0 += ka; x1 += kb + 3u;
  TF_ROUND(17); TF_ROUND(29); TF_ROUND(16); TF_ROUND(24);
  x0 += kb; x1 += ks2 + 4u;
  TF_ROUND(13); TF_ROUND(15); TF_ROUND(26); TF_ROUND(6);
  x0 += ks2; x1 += ka + 5u;
  o0 = x0; o1 = x1;
}

__device__ __forceinline__ unsigned rb32(unsigned ka, unsigned kb, unsigned i) {
  unsigned o0, o1; tf2(ka, kb, 0u, i, o0, o1); return o0 ^ o1;
}

__device__ __forceinline__ double pow7(double x) {
  const double x2 = x * x, x4 = x2 * x2;
  return x4 * x2 * x;
}

__device__ __forceinline__ unsigned catAt(unsigned w0, unsigned w1, unsigned w2,
                                          unsigned site) {
  const unsigned ww = (site < 16u) ? w0 : ((site < 32u) ? w1 : w2);
  return (ww >> (2u * (site & 15u))) & 3u;
}

__device__ __forceinline__ unsigned site_from_key(unsigned s) {
  unsigned ka, kb;  tf2(0u, 42u, 0u, s, ka, kb);
  unsigned i0, i1, h1a, h1b, l1a, l1b;
  tf2(ka, kb, 0u, 0u, i0, i1);
  tf2(i0, i1, 0u, 0u, h1a, h1b);
  tf2(i0, i1, 0u, 1u, l1a, l1b);
  const unsigned hb = rb32(h1a, h1b, 0u);
  const unsigned lb = rb32(l1a, l1b, 0u);
  return ((hb % 48u) * 16u + (lb % 48u)) % 48u;
}

#define PINV(x) asm volatile("" : "+v"(x))

// ---------------- phase 1: draws + tables ----------------
__global__ __launch_bounds__(256)
void draw_kernel(const float* __restrict__ h0, const float* __restrict__ modes_h,
                 const void* __restrict__ selp, unsigned char* __restrict__ ws) {
  const unsigned by = blockIdx.y;
  const unsigned t = threadIdx.x;
  if (by < (unsigned)kSteps) {
    // per-(step,chain) draws: packed (ub & ~511) | nc  (bit-identical to r5/r6)
    const unsigned s = by;
    const unsigned n = blockIdx.x * 256u + t;
    unsigned ka, kb;  tf2(0u, 42u, 0u, s, ka, kb);
    unsigned r0, r1, a0, a1, c0, c1;
    tf2(ka, kb, 0u, 1u, r0, r1);
    tf2(ka, kb, 0u, 2u, a0, a1);
    tf2(r0, r1, 0u, 1u, c0, c1);
    const unsigned nc = rb32(c0, c1, n) & 3u;
    const unsigned ub = rb32(a0, a1, n);
    ((unsigned*)(ws + DRAWS_OFF))[s * (unsigned)kN + n] = (ub & 0xFFFFFE00u) | nc;
    return;
  }
  if (blockIdx.x != 0) return;

  // ---- table block ----
  __shared__ unsigned ss[kSteps];
  __shared__ double exl[kL][5][4][2];   // [l][field: h,m0..3][cat][{+,-}]

  // phase 1: sites (t<48), exp singles (items t<240), bb weights (t==255)
  if (t < (unsigned)kSteps) ss[t] = site_from_key(t);
  if (t < 240u) {
    const int l = t / 5, k = t % 5;
#pragma unroll
    for (int c = 0; c < 4; ++c) {
      const double v = (k == 0) ? (double)h0[l * 4 + c]
                                : (double)modes_h[((k - 1) * kL + l) * 4 + c];
      exl[l][k][c][0] = exp(v);
      exl[l][k][c][1] = exp(-v);
    }
  }
  if (t == 255u) {
    const unsigned* wp = (const unsigned*)selp;
    int mode;
    if (wp[0] == 0x3F800000u) mode = 0;
    else {
      mode = 1;
      for (int i = 0; i < kR * kM; ++i) if (wp[i] > 1u) { mode = 2; break; }
    }
    double* bbw = (double*)(ws + BB_OFF);
    for (int r = 0; r < kR; ++r)
      for (int m = 1; m < kM; ++m) {
        const int i = r * 4 + m;
        unsigned b;
        if (mode == 0)      b = (wp[i] == 0x3F800000u) ? 1u : 0u;
        else if (mode == 1) b = wp[i] ? 1u : 0u;
        else                b = ((const unsigned char*)selp)[i] ? 1u : 0u;
        bbw[r * 3 + (m - 1)] = b ? 1.0 : 0.0;
      }
  }
  __syncthreads();

  // phase 2: meta, pair-factor rows, singles region
  if (t < (unsigned)kSteps) {
    unsigned* meta = (unsigned*)(ws + META_OFF);
    const unsigned flag = (t > 0u && ss[t] == ss[t - 1]) ? 1u : 0u;
    meta[2 * t]     = ss[t] * 1280u;
    meta[2 * t + 1] = ss[t] | (flag << 8);
    if (t == 0u) {
      meta[2 * 48] = ss[47] * 1280u;  meta[2 * 48 + 1] = ss[47];
      meta[2 * 49] = ss[47] * 1280u;  meta[2 * 49 + 1] = ss[47];
    }
  }
  // rows: 768 rows, 3 per thread
  for (int R = t; R < kL * 16; R += 256) {
    const int l = R >> 4, idx = R & 15, nw = idx >> 2, od = idx & 3;
    double* row = (double*)(ws + ROWS_OFF + (size_t)R * 80);
#pragma unroll
    for (int m = 0; m < 4; ++m) {
      row[m]     = exl[l][1 + m][nw][0] * exl[l][1 + m][od][1];  // fe_m
      row[4 + m] = exl[l][1 + m][nw][1] * exl[l][1 + m][od][0];  // fd_m
    }
    row[8] = exl[l][0][nw][0] * exl[l][0][od][1];                // fh
    row[9] = 0.0;
  }
  // singles: [l][c] -> 8 doubles {m0p,m0n,m1p,m1n,m2p,m2n,m3p,m3n}
  if (t < 192u) {
    const int l = t >> 2, c = t & 3;
    double* sg = (double*)(ws + SING_OFF + (size_t)(l * 4 + c) * 64);
#pragma unroll
    for (int m = 0; m < 4; ++m) {
      sg[2 * m]     = exl[l][1 + m][c][0];
      sg[2 * m + 1] = exl[l][1 + m][c][1];
    }
  }
}

// ---------------- phase 2: MCMC, pure LDS-table machine ----------------
__global__ __launch_bounds__(64, 1)
void mcmc_tab(const float* __restrict__ chains, const unsigned char* __restrict__ ws,
              float* __restrict__ out) {
  __shared__ __align__(16) char sTab[TAB_BYTES];
  __shared__ unsigned sDraws[50 * 64];

  const int tid = threadIdx.x;
  const int n = blockIdx.x * 64 + tid;

  // ---- stage tables + draws into LDS ----
  {
    const float4* gt = (const float4*)(ws + ROWS_OFF);
    float4* lt = (float4*)sTab;
    for (int i = tid; i < TAB_BYTES / 16; i += 64) lt[i] = gt[i];
    const unsigned* gd = (const unsigned*)(ws + DRAWS_OFF);
    for (int s = 0; s < kSteps; ++s)
      sDraws[s * 64 + tid] = gd[(size_t)s * kN + blockIdx.x * 64 + tid];
    sDraws[48 * 64 + tid] = 0u;
    sDraws[49 * 64 + tid] = 0u;
  }

  // ---- decode chain state: 2 bits/site (overlaps staging latency) ----
  unsigned w0 = 0, w1 = 0, w2 = 0;
  {
    const float4* ch = (const float4*)(chains + (size_t)n * (kL * 4));
#pragma unroll
    for (int l = 0; l < kL; ++l) {
      const float4 v = ch[l];
      const unsigned c = (v.y > 0.5f) ? 1u : ((v.z > 0.5f) ? 2u : ((v.w > 0.5f) ? 3u : 0u));
      const unsigned sh = 2u * (unsigned)(l & 15);
      if (l < 16) w0 |= c << sh; else if (l < 32) w1 |= c << sh; else w2 |= c << sh;
    }
  }
  __syncthreads();

  // ---- selection weights into pinned VGPRs (b0 == 1 by construction) ----
  double b1[kR], b2[kR], b3[kR];
  {
    const double* bbw = (const double*)(sTab + BB_OFF);
#pragma unroll
    for (int r = 0; r < kR; ++r) {
      b1[r] = bbw[r * 3 + 0];  PINV(b1[r]);
      b2[r] = bbw[r * 3 + 1];  PINV(b2[r]);
      b3[r] = bbw[r * 3 + 2];  PINV(b3[r]);
    }
  }

  // ---- initial multiplicative state from singles ----
  double e0 = 1.0, e1 = 1.0, e2 = 1.0, e3 = 1.0;
  double d0 = 1.0, d1 = 1.0, d2 = 1.0, d3 = 1.0;
#pragma unroll 4
  for (int l = 0; l < kL; ++l) {
    const unsigned c = catAt(w0, w1, w2, (unsigned)l);
    const double* sg = (const double*)(sTab + SING_OFF + (size_t)(l * 4 + c) * 64);
    e0 *= sg[0]; d0 *= sg[1];  e1 *= sg[2]; d1 *= sg[3];
    e2 *= sg[4]; d2 *= sg[5];  e3 *= sg[6]; d3 *= sg[7];
  }
  double Dd = pow7((d0 + d1) + (d2 + d3));
#pragma unroll
  for (int r = 0; r < kR; ++r)
    Dd *= (fma(b1[r], e1, e0) + fma(b3[r], e3, b2[r] * e2));

  // ---- pipeline prologue: step-0 row exact ----
  const unsigned* meta = (const unsigned*)(sTab + META_OFF);
  unsigned dwv[2];
  dwv[0] = sDraws[tid];
  dwv[1] = sDraws[64 + tid];
  double2 fe01[2], fe23[2], fd01[2], fd23[2];
  double fh[2];
  unsigned scur;
  {
    const unsigned off0 = meta[0];
    scur = meta[1] & 0xFFu;
    const unsigned idx0 = (dwv[0] & 3u) * 4u + catAt(w0, w1, w2, scur);
    const char* rb = sTab + off0 + idx0 * 80u;
    fe01[0] = *(const double2*)(rb);      fe23[0] = *(const double2*)(rb + 16);
    fd01[0] = *(const double2*)(rb + 32); fd23[0] = *(const double2*)(rb + 48);
    fh[0]   = *(const double*)(rb + 64);
  }

  // ---- 48 steps, x2 unrolled; slot parity = s & 1 ----
  for (int sb = 0; sb < kSteps; sb += 2) {
#pragma unroll
    for (int u = 0; u < 2; ++u) {
      const int s = sb + u;
      const int cu = u, nx = u ^ 1;
      const unsigned dcur = dwv[cu];

      // -- prefetch row for step s+1 (uses pre-update w; alt under flag) --
      const unsigned m0 = meta[2 * (s + 1)];
      const unsigned m1 = meta[2 * (s + 1) + 1];
      const unsigned nc1 = dwv[nx] & 3u;
      const unsigned oldc1 = catAt(w0, w1, w2, m1 & 0xFFu);
      {
        const char* rb = sTab + m0 + (nc1 * 4u + oldc1) * 80u;
        fe01[nx] = *(const double2*)(rb);      fe23[nx] = *(const double2*)(rb + 16);
        fd01[nx] = *(const double2*)(rb + 32); fd23[nx] = *(const double2*)(rb + 48);
        fh[nx]   = *(const double*)(rb + 64);
      }
      const bool flag1 = (m1 >> 8) & 1u;
      double2 xe01, xe23, xd01, xd23; double xh;
      if (flag1) {   // adjacent collision: also load row with oldc = nc_s
        const char* ra = sTab + m0 + (nc1 * 4u + (dcur & 3u)) * 80u;
        xe01 = *(const double2*)(ra);      xe23 = *(const double2*)(ra + 16);
        xd01 = *(const double2*)(ra + 32); xd23 = *(const double2*)(ra + 48);
        xh   = *(const double*)(ra + 64);
      }

      // -- compute step s --
      const float rndf = __uint_as_float((dcur >> 9) | 0x3F800000u) - 1.0f;
      const double f0 = e0 * fe01[cu].x, f1 = e1 * fe01[cu].y;
      const double f2 = e2 * fe23[cu].x, f3 = e3 * fe23[cu].y;
      const double g0 = d0 * fd01[cu].x, g1 = d1 * fd01[cu].y;
      const double g2 = d2 * fd23[cu].x, g3 = d3 * fd23[cu].y;
      double se[kR];
#pragma unroll
      for (int r = 0; r < kR; ++r)
        se[r] = fma(b1[r], f1, f0) + fma(b3[r], f3, b2[r] * f2);
      const double PQ = (pow7((g0 + g1) + (g2 + g3)) *
                         ((se[0] * se[1]) * (se[2] * se[3]))) *
                        ((se[4] * se[5]) * se[6]);
      const double N = fh[cu] * PQ;
      const bool acc = N > (double)rndf * Dd;

      // -- branch-free state update --
      const unsigned nc_c = dcur & 3u;
      const unsigned sh = 2u * (scur & 15u);
      const unsigned mb = 3u << sh, nv = nc_c << sh;
      const bool in0 = scur < 16u, in1 = (scur >= 16u) & (scur < 32u);
      w0 = (acc && in0) ? ((w0 & ~mb) | nv) : w0;
      w1 = (acc && in1) ? ((w1 & ~mb) | nv) : w1;
      w2 = (acc && !(in0 || in1)) ? ((w2 & ~mb) | nv) : w2;
      e0 = acc ? f0 : e0; e1 = acc ? f1 : e1; e2 = acc ? f2 : e2; e3 = acc ? f3 : e3;
      d0 = acc ? g0 : d0; d1 = acc ? g1 : d1; d2 = acc ? g2 : d2; d3 = acc ? g3 : d3;
      Dd = acc ? PQ : Dd;

      // -- resolve speculative row on (rare, uniform-flagged) collision --
      if (flag1) {
        fe01[nx].x = acc ? xe01.x : fe01[nx].x;  fe01[nx].y = acc ? xe01.y : fe01[nx].y;
        fe23[nx].x = acc ? xe23.x : fe23[nx].x;  fe23[nx].y = acc ? xe23.y : fe23[nx].y;
        fd01[nx].x = acc ? xd01.x : fd01[nx].x;  fd01[nx].y = acc ? xd01.y : fd01[nx].y;
        fd23[nx].x = acc ? xd23.x : fd23[nx].x;  fd23[nx].y = acc ? xd23.y : fd23[nx].y;
        fh[nx]     = acc ? xh     : fh[nx];
      }

      scur = m1 & 0xFFu;
      dwv[cu] = sDraws[(s + 2) * 64 + tid];   // draw for step s+2 -> slot s&1
    }
  }

  // ---- write one-hot output ----
  float4* o = (float4*)(out + (size_t)n * (kL * 4));
#pragma unroll
  for (int l = 0; l < kL; ++l) {
    const unsigned c = catAt(w0, w1, w2, (unsigned)l);
    o[l] = make_float4(c == 0u ? 1.0f : 0.0f, c == 1u ? 1.0f : 0.0f,
                       c == 2u ? 1.0f : 0.0f, c == 3u ? 1.0f : 0.0f);
  }
}

// ---------------- fallback (small ws): self-contained r5-style kernel ----------------
__device__ __forceinline__ void build_selB(const void* selp, double (*sB)[4]) {
  const unsigned* wp = (const unsigned*)selp;
  int mode;
  if (wp[0] == 0x3F800000u) mode = 0;
  else {
    mode = 1;
    for (int i = 0; i < kR * kM; ++i) if (wp[i] > 1u) { mode = 2; break; }
  }
  for (int r = 0; r < kR; ++r)
    for (int m = 0; m < kM; ++m) {
      const int i = r * 4 + m;
      unsigned b;
      if (mode == 0)      b = (wp[i] == 0x3F800000u) ? 1u : 0u;
      else if (mode == 1) b = wp[i] ? 1u : 0u;
      else                b = ((const unsigned char*)selp)[i] ? 1u : 0u;
      sB[r][m] = b ? 1.0 : 0.0;
    }
}

__global__ __launch_bounds__(64, 1)
void mcmc_loop(const float* __restrict__ chains, const float* __restrict__ h0,
               const float* __restrict__ modes_h, const void* __restrict__ selp,
               float* __restrict__ out) {
  __shared__ double2 sEH[kL][4];
  __shared__ double2 sEM[kM][kL][4];
  __shared__ double  sFH[kL][16];
  __shared__ double2 sFM[kM][kL][16];
  __shared__ unsigned sSite[64];
  __shared__ uint2 sCK[64], sAK[64];
  __shared__ double sB[kR][4];

  const int tid = threadIdx.x;
  for (int i = tid; i < kL * 4; i += 64) {
    const double v = (double)h0[i];
    sEH[i >> 2][i & 3] = make_double2(exp(v), exp(-v));
  }
  for (int i = tid; i < kM * kL * 4; i += 64) {
    const double v = (double)modes_h[i];
    sEM[i / (kL * 4)][(i >> 2) % kL][i & 3] = make_double2(exp(v), exp(-v));
  }
  {
    const unsigned s = (unsigned)tid;
    if (s < (unsigned)kSteps) {
      unsigned ka, kb;  tf2(0u, 42u, 0u, s, ka, kb);
      unsigned i0, i1, r0, r1, a0, a1;
      tf2(ka, kb, 0u, 0u, i0, i1);
      tf2(ka, kb, 0u, 1u, r0, r1);
      tf2(ka, kb, 0u, 2u, a0, a1);
      unsigned h1a, h1b, l1a, l1b;
      tf2(i0, i1, 0u, 0u, h1a, h1b);
      tf2(i0, i1, 0u, 1u, l1a, l1b);
      const unsigned hb = rb32(h1a, h1b, 0u);
      const unsigned lb = rb32(l1a, l1b, 0u);
      sSite[s] = ((hb % 48u) * 16u + (lb % 48u)) % 48u;
      unsigned c0, c1;  tf2(r0, r1, 0u, 1u, c0, c1);
      sCK[s] = make_uint2(c0, c1);
      sAK[s] = make_uint2(a0, a1);
    } else {
      sSite[s] = 0u; sCK[s] = make_uint2(0u, 0u); sAK[s] = make_uint2(0u, 0u);
    }
  }
  if (tid == 0) build_selB(selp, sB);
  __syncthreads();
  for (int i = tid; i < kL * 16; i += 64) {
    const int l = i >> 4, p = i & 15, nw = p >> 2, od = p & 3;
    sFH[l][p] = sEH[l][nw].x * sEH[l][od].y;
#pragma unroll
    for (int m = 0; m < kM; ++m)
      sFM[m][l][p] = make_double2(sEM[m][l][nw].x * sEM[m][l][od].y,
                                  sEM[m][l][nw].y * sEM[m][l][od].x);
  }
  __syncthreads();

  const int n = blockIdx.x * 64 + tid;
  double bb[kR][4];
#pragma unroll
  for (int r = 0; r < kR; ++r)
#pragma unroll
    for (int m = 0; m < 4; ++m) { bb[r][m] = sB[r][m]; PINV(bb[r][m]); }

  unsigned w0 = 0, w1 = 0, w2 = 0;
  {
    const float4* ch = (const float4*)(chains + (size_t)n * (kL * 4));
#pragma unroll
    for (int l = 0; l < kL; ++l) {
      const float4 v = ch[l];
      const unsigned c = (v.y > 0.5f) ? 1u : ((v.z > 0.5f) ? 2u : ((v.w > 0.5f) ? 3u : 0u));
      const unsigned sh = 2u * (unsigned)(l & 15);
      if (l < 16) w0 |= c << sh; else if (l < 32) w1 |= c << sh; else w2 |= c << sh;
    }
  }
  double e0 = 1.0, e1 = 1.0, e2 = 1.0, e3 = 1.0;
  double d0 = 1.0, d1 = 1.0, d2 = 1.0, d3 = 1.0;
#pragma unroll 4
  for (int l = 0; l < kL; ++l) {
    const unsigned c = catAt(w0, w1, w2, (unsigned)l);
    const double2 t0 = sEM[0][l][c], t1 = sEM[1][l][c];
    const double2 t2 = sEM[2][l][c], t3 = sEM[3][l][c];
    e0 *= t0.x; d0 *= t0.y;  e1 *= t1.x; d1 *= t1.y;
    e2 *= t2.x; d2 *= t2.y;  e3 *= t3.x; d3 *= t3.y;
  }
  double Dd = pow7((d0 + d1) + (d2 + d3));
#pragma unroll
  for (int r = 0; r < kR; ++r)
    Dd *= (fma(bb[r][1], e1, bb[r][0] * e0) + fma(bb[r][3], e3, bb[r][2] * e2));

  unsigned dw_c, dw_n;
  { const uint2 c0 = sCK[0], a0 = sAK[0];
    dw_c = (rb32(a0.x, a0.y, (unsigned)n) & 0xFFFFFE00u) |
           (rb32(c0.x, c0.y, (unsigned)n) & 3u); }
  { const uint2 c1 = sCK[1], a1 = sAK[1];
    dw_n = (rb32(a1.x, a1.y, (unsigned)n) & 0xFFFFFE00u) |
           (rb32(c1.x, c1.y, (unsigned)n) & 3u); }

  unsigned site_c = sSite[0];
  unsigned nc_c = dw_c & 3u;
  double fh_c;  double2 fm_c[4];
  {
    const unsigned idx = nc_c * 4u + catAt(w0, w1, w2, site_c);
    fh_c = sFH[site_c][idx];
#pragma unroll
    for (int m = 0; m < 4; ++m) fm_c[m] = sFM[m][site_c][idx];
  }

  for (int s = 0; s < kSteps; ++s) {
    const uint2 c2 = sCK[s + 2], a2 = sAK[s + 2];
    const unsigned dw_f = (rb32(a2.x, a2.y, (unsigned)n) & 0xFFFFFE00u) |
                          (rb32(c2.x, c2.y, (unsigned)n) & 3u);
    const unsigned site_n = sSite[s + 1];
    const unsigned nc_n = dw_n & 3u;
    const unsigned oldc_n = catAt(w0, w1, w2, site_n);
    double fh_n = sFH[site_n][nc_n * 4u + oldc_n];
    double2 fm_n[4];
#pragma unroll
    for (int m = 0; m < 4; ++m) fm_n[m] = sFM[m][site_n][nc_n * 4u + oldc_n];

    const float rndf = __uint_as_float((dw_c >> 9) | 0x3F800000u) - 1.0f;
    const double f0 = e0 * fm_c[0].x, g0 = d0 * fm_c[0].y;
    const double f1 = e1 * fm_c[1].x, g1 = d1 * fm_c[1].y;
    const double f2 = e2 * fm_c[2].x, g2 = d2 * fm_c[2].y;
    const double f3 = e3 * fm_c[3].x, g3 = d3 * fm_c[3].y;
    double se[kR];
#pragma unroll
    for (int r = 0; r < kR; ++r)
      se[r] = fma(bb[r][1], f1, bb[r][0] * f0) + fma(bb[r][3], f3, bb[r][2] * f2);
    const double PQ = (pow7((g0 + g1) + (g2 + g3)) *
                       ((se[0] * se[1]) * (se[2] * se[3]))) *
                      ((se[4] * se[5]) * se[6]);
    const double N = fh_c * PQ;
    const bool acc = N > (double)rndf * Dd;

    const unsigned sh = 2u * (site_c & 15u);
    const unsigned mb = 3u << sh, nv = nc_c << sh;
    const bool in0 = site_c < 16u, in1 = (site_c >= 16u) & (site_c < 32u);
    w0 = (acc && in0) ? ((w0 & ~mb) | nv) : w0;
    w1 = (acc && in1) ? ((w1 & ~mb) | nv) : w1;
    w2 = (acc && !(in0 || in1)) ? ((w2 & ~mb) | nv) : w2;
    e0 = acc ? f0 : e0; e1 = acc ? f1 : e1; e2 = acc ? f2 : e2; e3 = acc ? f3 : e3;
    d0 = acc ? g0 : d0; d1 = acc ? g1 : d1; d2 = acc ? g2 : d2; d3 = acc ? g3 : d3;
    Dd = acc ? PQ : Dd;

    if (site_n == site_c) {
      const unsigned to = acc ? nc_c : oldc_n;
      const unsigned i2 = nc_n * 4u + to;
      fh_n = sFH[site_n][i2];
#pragma unroll
      for (int m = 0; m < 4; ++m) fm_n[m] = sFM[m][site_n][i2];
    }
    site_c = site_n; nc_c = nc_n; dw_c = dw_n; dw_n = dw_f;
    fh_c = fh_n;
#pragma unroll
    for (int m = 0; m < 4; ++m) fm_c[m] = fm_n[m];
  }

  float4* o = (float4*)(out + (size_t)n * (kL * 4));
#pragma unroll
  for (int l = 0; l < kL; ++l) {
    const unsigned c = catAt(w0, w1, w2, (unsigned)l);
    o[l] = make_float4(c == 0u ? 1.0f : 0.0f, c == 1u ? 1.0f : 0.0f,
                       c == 2u ? 1.0f : 0.0f, c == 3u ? 1.0f : 0.0f);
  }
}

extern "C" void kernel_launch(void* const* d_in, const int* in_sizes, int n_in,
                              void* d_out, int out_size, void* d_ws, size_t ws_size,
                              hipStream_t stream) {
  const float* chains  = (const float*)d_in[0];
  const float* h0      = (const float*)d_in[1];
  const float* modes_h = (const float*)d_in[2];
  const void*  sel     = d_in[3];
  (void)in_sizes; (void)n_in; (void)out_size;

  const size_t need = (size_t)DRAWS_OFF + (size_t)kSteps * kN * sizeof(unsigned);
  if (ws_size >= need) {
    unsigned char* ws = (unsigned char*)d_ws;
    draw_kernel<<<dim3(kN / 256, kSteps + 1), dim3(256), 0, stream>>>(
        h0, modes_h, sel, ws);
    mcmc_tab<<<dim3(kN / 64), dim3(64), 0, stream>>>(chains, ws, (float*)d_out);
  } else {
    mcmc_loop<<<dim3(kN / 64), dim3(64), 0, stream>>>(
        chains, h0, modes_h, sel, (float*)d_out);
  }
}